// Round 13
// baseline (40675.226 us; speedup 1.0000x reference)
//
#include <hip/hip_runtime.h>

#define D_ 512
#define FF_ 1024
#define L_ 4
#define A_ 32
#define B_ 1024
#define STEPS_ 64
#define RB8_ 0.15f    // fp8 GEMM2 rescue band: >=5 sigma
#define DIAG_STEPS_ 256   // 4x steps so diagnostics rank in top-5 dispatches
#define SCRMASK_ 0x3FFFF  // 1MB float scratch ring for diagnostic outputs

typedef __attribute__((ext_vector_type(8))) short bf16x8;
typedef __attribute__((ext_vector_type(4))) float f32x4;
typedef __attribute__((ext_vector_type(2))) unsigned long u64x2;
#define MFMA16(a,b,c) __builtin_amdgcn_mfma_f32_16x16x32_bf16(a,b,c,0,0,0)
#define MFMA8(a,b,c)  __builtin_amdgcn_mfma_f32_16x16x32_fp8_fp8((long)(a),(long)(b),(c),0,0,0)

__device__ __forceinline__ unsigned rne16(float f) {
    unsigned u = __float_as_uint(f);
    return (u + 0x7fffu + ((u >> 16) & 1u)) >> 16;
}
__device__ __forceinline__ float fb(unsigned hu) { return __uint_as_float(hu << 16); }

// ---- asm load/wait primitives (R9/R10-verified) ------------------------------
#define LD4(R0, R1, R2, R3, P0_, P1_, P2_, P3_)                                \
    asm volatile("global_load_dwordx4 %0, %4, off\n\t"                         \
                 "global_load_dwordx4 %1, %5, off\n\t"                         \
                 "global_load_dwordx4 %2, %6, off\n\t"                         \
                 "global_load_dwordx4 %3, %7, off"                             \
                 : "=&v"(R0), "=&v"(R1), "=&v"(R2), "=&v"(R3)                  \
                 : "v"(P0_), "v"(P1_), "v"(P2_), "v"(P3_))

#define WAIT4(N, R0, R1, R2, R3)                                               \
    asm volatile("s_waitcnt vmcnt(" #N ")"                                     \
                 : "+v"(R0), "+v"(R1), "+v"(R2), "+v"(R3) :: "memory")

// ---------------- Wvo[l] = Wv[l] @ Wo[l], split-bf16 MFMA fragments ------------
__global__ __launch_bounds__(256) void wvo_kernel(
    const float* __restrict__ Wv, const float* __restrict__ Wo,
    unsigned* __restrict__ Whi, unsigned* __restrict__ Wlo)
{
    __shared__ float wvt[16][D_];
    int bx  = blockIdx.x;
    int l   = bx >> 6;
    int rem = bx & 63;
    int k0  = (rem >> 1) * 16;
    int n   = (rem & 1) * 256 + threadIdx.x;

    const float* wvbase = Wv + (size_t)l * D_ * D_ + (size_t)k0 * D_;
    for (int idx = threadIdx.x; idx < 16 * D_; idx += 256)
        wvt[idx >> 9][idx & (D_ - 1)] = wvbase[idx];
    __syncthreads();

    float acc[16];
#pragma unroll
    for (int kk = 0; kk < 16; ++kk) acc[kk] = 0.f;

    const float* wop = Wo + (size_t)l * D_ * D_ + n;
    for (int m = 0; m < D_; m += 4) {
        float w0 = wop[(m + 0) * D_];
        float w1 = wop[(m + 1) * D_];
        float w2 = wop[(m + 2) * D_];
        float w3 = wop[(m + 3) * D_];
#pragma unroll
        for (int kk = 0; kk < 16; ++kk) {
            float4 wv4 = *(const float4*)&wvt[kk][m];
            acc[kk] += wv4.x * w0 + wv4.y * w1 + wv4.z * w2 + wv4.w * w3;
        }
    }
    int nt = n >> 4, ln15 = n & 15;
    int kkblk = k0 >> 5;
    int gbase = (k0 & 31) >> 3;
#pragma unroll
    for (int gi = 0; gi < 2; ++gi) {
        int lane_s = ((gbase + gi) << 4) | ln15;
        size_t fbase = ((((size_t)l * 32 + nt) * 16 + kkblk) * 64 + lane_s) * 4;
#pragma unroll
        for (int jp = 0; jp < 4; ++jp) {
            float v0 = acc[gi * 8 + jp * 2], v1 = acc[gi * 8 + jp * 2 + 1];
            unsigned h0 = rne16(v0), h1 = rne16(v1);
            Whi[fbase + jp] = h0 | (h1 << 16);
            float r0 = v0 - fb(h0), r1 = v1 - fb(h1);
            Wlo[fbase + jp] = rne16(r0) | (rne16(r1) << 16);
        }
    }
}

// ---------------- bvo[l] = bv[l] @ Wo[l] + bo[l] -------------------------------
__global__ __launch_bounds__(256) void bvo_kernel(
    const float* __restrict__ bv, const float* __restrict__ bo,
    const float* __restrict__ Wo, float* __restrict__ bvo)
{
    int l = blockIdx.x >> 1;
    int n = (blockIdx.x & 1) * 256 + threadIdx.x;
    float acc = bo[l * D_ + n];
    const float* wop = Wo + (size_t)l * D_ * D_ + n;
    const float* bvp = bv + l * D_;
    for (int m = 0; m < D_; ++m) acc += bvp[m] * wop[m * D_];
    bvo[l * D_ + n] = acc;
}

// ---------------- Wf1 -> fp8 e4m3 MFMA fragments, x16 scaled, kk-pair packed ----
__global__ __launch_bounds__(64) void packwf1_fp8(
    const float* __restrict__ Wf1, unsigned char* __restrict__ Pf8)
{
    int bid = blockIdx.x;              // 4*64*8 = 2048
    int lane = threadIdx.x;
    int l  = bid >> 9;
    int nt = (bid >> 3) & 63;
    int p  = bid & 7;
    int n  = nt * 16 + (lane & 15);
    unsigned w[4];
#pragma unroll
    for (int half = 0; half < 2; ++half) {
        int kk = 2 * p + half;
        int krow = kk * 32 + (lane >> 4) * 8;
        const float* src = Wf1 + ((size_t)l * D_ + krow) * FF_ + n;
        float f0 = src[0 * FF_] * 16.f, f1 = src[1 * FF_] * 16.f;
        float f2 = src[2 * FF_] * 16.f, f3 = src[3 * FF_] * 16.f;
        float f4 = src[4 * FF_] * 16.f, f5 = src[5 * FF_] * 16.f;
        float f6 = src[6 * FF_] * 16.f, f7 = src[7 * FF_] * 16.f;
        unsigned lo = 0, hi = 0;
        lo = __builtin_amdgcn_cvt_pk_fp8_f32(f0, f1, lo, false);
        lo = __builtin_amdgcn_cvt_pk_fp8_f32(f2, f3, lo, true);
        hi = __builtin_amdgcn_cvt_pk_fp8_f32(f4, f5, hi, false);
        hi = __builtin_amdgcn_cvt_pk_fp8_f32(f6, f7, hi, true);
        w[half * 2] = lo; w[half * 2 + 1] = hi;
    }
    uint4 o; o.x = w[0]; o.y = w[1]; o.z = w[2]; o.w = w[3];
    ((uint4*)Pf8)[((size_t)(l * 64 + nt) * 8 + p) * 64 + lane] = o;
}

// ---------------- LN1: xb -> bf16 A-fragments (R3-verified) --------------------
__device__ __forceinline__ void layer_norm_frag(
    float (*xb)[D_], unsigned* __restrict__ afrag,
    const float* __restrict__ g, const float* __restrict__ bt,
    float (*red)[4][2], int sg, int r)
{
    int c = 2 * r;
    float v0 = xb[sg][c], v1 = xb[sg][c + 1];
    float s  = v0 + v1;
    float ss = v0 * v0 + v1 * v1;
#pragma unroll
    for (int m = 1; m < 64; m <<= 1) {
        s  += __shfl_xor(s, m);
        ss += __shfl_xor(ss, m);
    }
    if ((r & 63) == 0) { red[sg][r >> 6][0] = s; red[sg][r >> 6][1] = ss; }
    __syncthreads();
    float S  = red[sg][0][0] + red[sg][1][0] + red[sg][2][0] + red[sg][3][0];
    float SS = red[sg][0][1] + red[sg][1][1] + red[sg][2][1] + red[sg][3][1];
    float mean = S * (1.f / 512.f);
    float var  = SS * (1.f / 512.f) - mean * mean;
    float rstd = 1.0f / sqrtf(var + 1e-5f);
    float h0 = (v0 - mean) * rstd * g[c]     + bt[c];
    float h1 = (v1 - mean) * rstd * g[c + 1] + bt[c + 1];
    unsigned u0 = rne16(h0), u1 = rne16(h1);
    float l0 = h0 - fb(u0), l1 = h1 - fb(u1);
    int kk = c >> 5, grp = (c & 31) >> 3, jp = (c & 7) >> 1;
    afrag[(kk * 64 + ((grp << 4) | sg))       * 4 + jp] = u0 | (u1 << 16);
    afrag[(kk * 64 + ((grp << 4) | (sg + 4))) * 4 + jp] = rne16(l0) | (rne16(l1) << 16);
    __syncthreads();
}

// ---------------- LN2: xb -> fp8 A-fragments; saves mean/rstd for rescue -------
__device__ __forceinline__ void ln2_pack8(
    float (*xb)[D_], unsigned short* __restrict__ afrag8,
    const float* __restrict__ g, const float* __restrict__ bt,
    float (*red)[4][2], float* __restrict__ ln2m, float* __restrict__ ln2r,
    int sg, int r)
{
    int c = 2 * r;
    float v0 = xb[sg][c], v1 = xb[sg][c + 1];
    float s  = v0 + v1;
    float ss = v0 * v0 + v1 * v1;
#pragma unroll
    for (int m = 1; m < 64; m <<= 1) {
        s  += __shfl_xor(s, m);
        ss += __shfl_xor(ss, m);
    }
    if ((r & 63) == 0) { red[sg][r >> 6][0] = s; red[sg][r >> 6][1] = ss; }
    __syncthreads();
    float S  = red[sg][0][0] + red[sg][1][0] + red[sg][2][0] + red[sg][3][0];
    float SS = red[sg][0][1] + red[sg][1][1] + red[sg][2][1] + red[sg][3][1];
    float mean = S * (1.f / 512.f);
    float var  = SS * (1.f / 512.f) - mean * mean;
    float rstd = 1.0f / sqrtf(var + 1e-5f);
    if (r == 0) { ln2m[sg] = mean; ln2r[sg] = rstd; }
    float h0 = (v0 - mean) * rstd * g[c]     + bt[c];
    float h1 = (v1 - mean) * rstd * g[c + 1] + bt[c + 1];
    unsigned u = __builtin_amdgcn_cvt_pk_fp8_f32(h0, h1, 0, false);
    int kk = c >> 5, grp = (c & 31) >> 3, j = c & 7;
    afrag8[(kk * 64 + ((grp << 4) | sg)) * 4 + (j >> 1)] = (unsigned short)u;
    __syncthreads();
}

// ---------------- persistent recurrence kernel (R10-EXACT, the scored kernel) --
__global__ __launch_bounds__(1024)
__attribute__((amdgpu_waves_per_eu(4, 4)))
void smain(
    const float* __restrict__ init_state,
    const float* __restrict__ acts,
    const float* __restrict__ Wa,  const float* __restrict__ ba,
    const float* __restrict__ ln1g, const float* __restrict__ ln1b,
    const float* __restrict__ ln2g, const float* __restrict__ ln2b,
    const float* __restrict__ Wf1, const float* __restrict__ bf1,
    const float* __restrict__ Wf2, const float* __restrict__ bf2,
    const float* __restrict__ lifth,
    const float* __restrict__ Wr,  const float* __restrict__ br,
    const unsigned* __restrict__ Whi, const unsigned* __restrict__ Wlo,
    const unsigned char* __restrict__ Pf8, const float* __restrict__ bvo,
    float* __restrict__ out_states, float* __restrict__ out_rewards,
    float* __restrict__ out_final)
{
    __shared__ __align__(16) unsigned afrag[16 * 64 * 4];
    __shared__ __align__(16) unsigned short afrag8[16 * 64 * 4];
    __shared__ __align__(16) float xb[4][D_];
    __shared__ float areg[4][A_];
    __shared__ float red[4][4][2];
    __shared__ float rr[16];
    __shared__ float ln2m[4], ln2r[4];
    __shared__ int   fire_cnt, resc_cnt;
    __shared__ int   fire_list[256];
    __shared__ int   rescue_list[64];

    const int tid  = threadIdx.x;
    const int sg   = tid >> 8;
    const int r    = tid & 255;
    const int wv   = tid >> 6;
    const int lane = tid & 63;
    const int b    = blockIdx.x * 4 + sg;

    float st0 = init_state[(size_t)b * D_ + r];
    float st1 = init_state[(size_t)b * D_ + r + 256];
#pragma unroll
    for (int z = 0; z < 4; ++z) afrag[tid + z * 1024] = 0;
    ((unsigned*)afrag8)[tid] = 0;
    ((unsigned*)afrag8)[tid + 1024] = 0;
    __syncthreads();

    for (int t = 0; t < STEPS_; ++t) {
        if (tid < 128) {
            int sg2 = tid >> 5, j = tid & 31;
            areg[sg2][j] = acts[((size_t)(blockIdx.x * 4 + sg2)) * (STEPS_ * A_) + t * A_ + j];
        }
        __syncthreads();

        {
            float x0 = st0 + ba[r];
            float x1 = st1 + ba[r + 256];
#pragma unroll
            for (int j = 0; j < A_; ++j) {
                float av = areg[sg][j];
                x0 += av * Wa[j * D_ + r];
                x1 += av * Wa[j * D_ + r + 256];
            }
            xb[sg][r] = x0; xb[sg][r + 256] = x1;
        }
        __syncthreads();

        for (int l = 0; l < L_; ++l) {
            layer_norm_frag(xb, afrag, ln1g + l * D_, ln1b + l * D_, red, sg, r);

            {
                const bf16x8* Ah = (const bf16x8*)afrag;
                const size_t lb = (size_t)l * (32 * 16 * 64);
                const bf16x8* BH0 = (const bf16x8*)Whi + lb + (size_t)(2 * wv) * (16 * 64) + lane;
                const bf16x8* BL0 = (const bf16x8*)Wlo + lb + (size_t)(2 * wv) * (16 * 64) + lane;
                const bf16x8* BH1 = BH0 + 16 * 64;
                const bf16x8* BL1 = BL0 + 16 * 64;
                f32x4 c1a = {0.f,0.f,0.f,0.f}, c2a = c1a, c1b = c1a, c2b = c1a;
                bf16x8 aH0, aG0, aH1, aG1;
                bf16x8 bH0, bG0, bH1, bG1;
                bf16x8 cH0, cG0, cH1, cG1;
#define G1LD(S, KK) LD4(S##H0, S##G0, S##H1, S##G1, \
                        BH0 + (KK) * 64, BL0 + (KK) * 64, BH1 + (KK) * 64, BL1 + (KK) * 64)
#define G1MM(S, KK) do { bf16x8 a_ = Ah[(KK) * 64 + lane]; \
    c1a = MFMA16(a_, S##H0, c1a); c2a = MFMA16(a_, S##G0, c2a); \
    c1b = MFMA16(a_, S##H1, c1b); c2b = MFMA16(a_, S##G1, c2b); } while (0)
#define G1W(N, S) WAIT4(N, S##H0, S##G0, S##H1, S##G1)
                G1LD(a, 0); G1LD(b, 1); G1LD(c, 2);
                G1W(8, a); G1MM(a, 0);  G1LD(a, 3);
                G1W(8, b); G1MM(b, 1);  G1LD(b, 4);
                G1W(8, c); G1MM(c, 2);  G1LD(c, 5);
                G1W(8, a); G1MM(a, 3);  G1LD(a, 6);
                G1W(8, b); G1MM(b, 4);  G1LD(b, 7);
                G1W(8, c); G1MM(c, 5);  G1LD(c, 8);
                G1W(8, a); G1MM(a, 6);  G1LD(a, 9);
                G1W(8, b); G1MM(b, 7);  G1LD(b, 10);
                G1W(8, c); G1MM(c, 8);  G1LD(c, 11);
                G1W(8, a); G1MM(a, 9);  G1LD(a, 12);
                G1W(8, b); G1MM(b, 10); G1LD(b, 13);
                G1W(8, c); G1MM(c, 11); G1LD(c, 14);
                G1W(8, a); G1MM(a, 12); G1LD(a, 15);
                G1W(8, b); G1MM(b, 13);
                G1W(4, c); G1MM(c, 14);
                G1W(0, a); G1MM(a, 15);
#undef G1LD
#undef G1MM
#undef G1W
                const int nt0 = 2 * wv, nt1 = nt0 + 1;
#pragma unroll
                for (int s = 0; s < 4; ++s) {
                    float pa = c1a[s] + c2a[s]; float qa = __shfl(pa, (lane & 15) + 16);
                    float pb = c1b[s] + c2b[s]; float qb = __shfl(pb, (lane & 15) + 16);
                    if (lane < 16) {
                        int ca = nt0 * 16 + lane, cb = nt1 * 16 + lane;
                        xb[s][ca] += pa + qa + bvo[l * D_ + ca];
                        xb[s][cb] += pb + qb + bvo[l * D_ + cb];
                    }
                }
            }
            __syncthreads();

            if (tid == 0) { fire_cnt = 0; resc_cnt = 0; }

            ln2_pack8(xb, afrag8, ln2g + l * D_, ln2b + l * D_, red, ln2m, ln2r, sg, r);

            {
                const unsigned long* Ah8 = (const unsigned long*)afrag8;
                const int m0 = 4 * wv;
                const u64x2* Q0 = (const u64x2*)Pf8 + ((size_t)(l * 64 + m0 + 0) * 8) * 64 + lane;
                const u64x2* Q1 = (const u64x2*)Pf8 + ((size_t)(l * 64 + m0 + 1) * 8) * 64 + lane;
                const u64x2* Q2 = (const u64x2*)Pf8 + ((size_t)(l * 64 + m0 + 2) * 8) * 64 + lane;
                const u64x2* Q3 = (const u64x2*)Pf8 + ((size_t)(l * 64 + m0 + 3) * 8) * 64 + lane;
                f32x4 p0 = {0.f,0.f,0.f,0.f}, p1 = p0, p2 = p0, p3 = p0;
                u64x2 aB0, aB1, aB2, aB3;
                u64x2 bB0, bB1, bB2, bB3;
                u64x2 cB0, cB1, cB2, cB3;
#define G2LD(S, P) LD4(S##B0, S##B1, S##B2, S##B3, \
                       Q0 + (P) * 64, Q1 + (P) * 64, Q2 + (P) * 64, Q3 + (P) * 64)
#define G2MM(S, P) do { \
    unsigned long a0_ = Ah8[(2 * (P))     * 64 + lane]; \
    unsigned long a1_ = Ah8[(2 * (P) + 1) * 64 + lane]; \
    p0 = MFMA8(a0_, S##B0.x, p0); p1 = MFMA8(a0_, S##B1.x, p1); \
    p2 = MFMA8(a0_, S##B2.x, p2); p3 = MFMA8(a0_, S##B3.x, p3); \
    p0 = MFMA8(a1_, S##B0.y, p0); p1 = MFMA8(a1_, S##B1.y, p1); \
    p2 = MFMA8(a1_, S##B2.y, p2); p3 = MFMA8(a1_, S##B3.y, p3); } while (0)
#define G2W(N, S) WAIT4(N, S##B0, S##B1, S##B2, S##B3)
                G2LD(a, 0); G2LD(b, 1); G2LD(c, 2);
                G2W(8, a); G2MM(a, 0); G2LD(a, 3);
                G2W(8, b); G2MM(b, 1); G2LD(b, 4);
                G2W(8, c); G2MM(c, 2); G2LD(c, 5);
                G2W(8, a); G2MM(a, 3); G2LD(a, 6);
                G2W(8, b); G2MM(b, 4); G2LD(b, 7);
                G2W(8, c); G2MM(c, 5);
                G2W(4, a); G2MM(a, 6);
                G2W(0, b); G2MM(b, 7);
#undef G2LD
#undef G2MM
#undef G2W
                const float* bf1g = bf1 + l * FF_;
#pragma unroll
                for (int s = 0; s < 4; ++s) {
                    float v0 = p0[s]; float w0 = __shfl(v0, (lane & 15) + 16);
                    float v1 = p1[s]; float w1 = __shfl(v1, (lane & 15) + 16);
                    float v2 = p2[s]; float w2 = __shfl(v2, (lane & 15) + 16);
                    float v3 = p3[s]; float w3 = __shfl(v3, (lane & 15) + 16);
                    if (lane < 16) {
#pragma unroll
                        for (int q = 0; q < 4; ++q) {
                            float sum = (q == 0) ? v0 + w0 : (q == 1) ? v1 + w1
                                       : (q == 2) ? v2 + w2 : v3 + w3;
                            int n = (m0 + q) * 16 + lane;
                            float pr = sum * 0.0625f + bf1g[n] - 2.0f;
                            if (pr > RB8_) {
                                int idx = atomicAdd(&fire_cnt, 1);
                                if (idx < 256) fire_list[idx] = (s << 12) | n;
                            } else if (pr > -RB8_) {
                                int idx = atomicAdd(&resc_cnt, 1);
                                if (idx < 64) rescue_list[idx] = (s << 12) | n;
                            }
                        }
                    }
                }
            }
            __syncthreads();

            {
                int rc = resc_cnt; if (rc > 64) rc = 64;
                const float* g2 = ln2g + l * D_;
                const float* b2 = ln2b + l * D_;
                for (int e = 0; e < rc; ++e) {
                    int ent = rescue_list[e];
                    int i = ent >> 12, n = ent & 4095;
                    float p = 0.f;
                    if (tid < D_) {
                        float hh = (xb[i][tid] - ln2m[i]) * ln2r[i] * g2[tid] + b2[tid];
                        p = hh * Wf1[((size_t)l * D_ + tid) * FF_ + n];
                    }
#pragma unroll
                    for (int m = 1; m < 64; m <<= 1) p += __shfl_xor(p, m);
                    if ((tid & 63) == 0) rr[tid >> 6] = p;
                    __syncthreads();
                    if (tid == 0) {
                        float dot = 0.f;
#pragma unroll
                        for (int w = 0; w < 8; ++w) dot += rr[w];
                        float pre = dot + bf1[l * FF_ + n] - 2.0f;
                        if (pre > 0.f) {
                            int idx = atomicAdd(&fire_cnt, 1);
                            if (idx < 256) fire_list[idx] = ent;
                        }
                    }
                    __syncthreads();
                }
            }

            {
                int cnt = fire_cnt; if (cnt > 256) cnt = 256;
                if (cnt > 0) {
                    for (int e = 0; e < cnt; ++e) {
                        int ent = fire_list[e];
                        int i = ent >> 12, n = ent & 4095;
                        if (tid < D_) xb[i][tid] += Wf2[(size_t)l * (FF_ * D_) + (size_t)n * D_ + tid];
                    }
                    __syncthreads();
                }
                xb[sg][r]       += bf2[l * D_ + r];
                xb[sg][r + 256] += bf2[l * D_ + r + 256];
            }
            __syncthreads();
        } // layers

        {
            float x0 = xb[sg][r], x1 = xb[sg][r + 256];
            float s0 = (x0 > lifth[r])       ? 1.0f : 0.0f;
            float s1 = (x1 > lifth[r + 256]) ? 1.0f : 0.0f;
            st0 = s0; st1 = s1;
            size_t so = ((size_t)b * STEPS_ + t) * D_;
            __builtin_nontemporal_store(s0, &out_states[so + r]);
            __builtin_nontemporal_store(s1, &out_states[so + r + 256]);

            float rs = s0 * Wr[r] + s1 * Wr[r + 256];
#pragma unroll
            for (int m = 1; m < 64; m <<= 1) rs += __shfl_xor(rs, m);
            if ((r & 63) == 0) red[sg][r >> 6][0] = rs;
            __syncthreads();
            if (r == 0)
                __builtin_nontemporal_store(
                    red[sg][0][0] + red[sg][1][0] + red[sg][2][0] + red[sg][3][0] + br[0],
                    &out_rewards[(size_t)b * STEPS_ + t]);
        }
        __syncthreads();
    } // steps

    __builtin_nontemporal_store(st0, &out_final[(size_t)b * D_ + r]);
    __builtin_nontemporal_store(st1, &out_final[(size_t)b * D_ + r + 256]);
}

// ================= DIAGNOSTIC: fixed-cost kernel (no GEMM loads/MFMA) ==========
// All LN/barriers/detect/epilogue intact; fires neutered; outputs -> scratch.
__global__ __launch_bounds__(1024)
__attribute__((amdgpu_waves_per_eu(4, 4)))
void diag_fixed(
    const float* __restrict__ init_state, const float* __restrict__ acts,
    const float* __restrict__ Wa,  const float* __restrict__ ba,
    const float* __restrict__ ln1g, const float* __restrict__ ln1b,
    const float* __restrict__ ln2g, const float* __restrict__ ln2b,
    const float* __restrict__ bf1, const float* __restrict__ bf2,
    const float* __restrict__ lifth, const float* __restrict__ Wr,
    const float* __restrict__ bvo, float* __restrict__ scr)
{
    __shared__ __align__(16) unsigned afrag[16 * 64 * 4];
    __shared__ __align__(16) unsigned short afrag8[16 * 64 * 4];
    __shared__ __align__(16) float xb[4][D_];
    __shared__ float areg[4][A_];
    __shared__ float red[4][4][2];
    __shared__ float ln2m[4], ln2r[4];
    __shared__ int   fire_cnt, resc_cnt;
    __shared__ int   fire_list[256];
    __shared__ int   rescue_list[64];

    const int tid  = threadIdx.x;
    const int sg   = tid >> 8;
    const int r    = tid & 255;
    const int wv   = tid >> 6;
    const int lane = tid & 63;
    const int b    = blockIdx.x * 4 + sg;

    float st0 = init_state[(size_t)b * D_ + r];
    float st1 = init_state[(size_t)b * D_ + r + 256];
#pragma unroll
    for (int z = 0; z < 4; ++z) afrag[tid + z * 1024] = 0;
    ((unsigned*)afrag8)[tid] = 0;
    ((unsigned*)afrag8)[tid + 1024] = 0;
    __syncthreads();

    for (int t = 0; t < DIAG_STEPS_; ++t) {
        if (tid < 128) {
            int sg2 = tid >> 5, j = tid & 31;
            areg[sg2][j] = acts[((size_t)(blockIdx.x * 4 + sg2)) * (STEPS_ * A_) + (t & 63) * A_ + j];
        }
        __syncthreads();
        {
            float x0 = st0 + ba[r];
            float x1 = st1 + ba[r + 256];
#pragma unroll
            for (int j = 0; j < A_; ++j) {
                float av = areg[sg][j];
                x0 += av * Wa[j * D_ + r];
                x1 += av * Wa[j * D_ + r + 256];
            }
            xb[sg][r] = x0; xb[sg][r + 256] = x1;
        }
        __syncthreads();

        for (int l = 0; l < L_; ++l) {
            layer_norm_frag(xb, afrag, ln1g + l * D_, ln1b + l * D_, red, sg, r);

            // GEMM1 stand-in: consume afrag (keeps LN live), no loads/MFMA
            {
                float v = __int_as_float(afrag[(lane * 67) & 4095]);
                f32x4 c1a = {v, v, v, v}, c2a = c1a, c1b = c1a, c2b = c1a;
                const int nt0 = 2 * wv, nt1 = nt0 + 1;
#pragma unroll
                for (int s = 0; s < 4; ++s) {
                    float pa = c1a[s] + c2a[s]; float qa = __shfl(pa, (lane & 15) + 16);
                    float pb = c1b[s] + c2b[s]; float qb = __shfl(pb, (lane & 15) + 16);
                    if (lane < 16) {
                        int ca = nt0 * 16 + lane, cb = nt1 * 16 + lane;
                        xb[s][ca] += pa + qa + bvo[l * D_ + ca];
                        xb[s][cb] += pb + qb + bvo[l * D_ + cb];
                    }
                }
            }
            __syncthreads();

            if (tid == 0) { fire_cnt = 0; resc_cnt = 0; }

            ln2_pack8(xb, afrag8, ln2g + l * D_, ln2b + l * D_, red, ln2m, ln2r, sg, r);

            // GEMM2 stand-in + detect with neutered thresholds (no fires ever)
            {
                float v = __int_as_float((unsigned)afrag8[(lane * 131) & 4095]);
                f32x4 p0 = {v, v, v, v}, p1 = p0, p2 = p0, p3 = p0;
                const int m0 = 4 * wv;
                const float* bf1g = bf1 + l * FF_;
#pragma unroll
                for (int s = 0; s < 4; ++s) {
                    float v0 = p0[s]; float w0 = __shfl(v0, (lane & 15) + 16);
                    float v1 = p1[s]; float w1 = __shfl(v1, (lane & 15) + 16);
                    float v2 = p2[s]; float w2 = __shfl(v2, (lane & 15) + 16);
                    float v3 = p3[s]; float w3 = __shfl(v3, (lane & 15) + 16);
                    if (lane < 16) {
#pragma unroll
                        for (int q = 0; q < 4; ++q) {
                            float sum = (q == 0) ? v0 + w0 : (q == 1) ? v1 + w1
                                       : (q == 2) ? v2 + w2 : v3 + w3;
                            int n = (m0 + q) * 16 + lane;
                            float pr = sum * 0.0625f + bf1g[n] - 2.0f;
                            if (pr > 1.0e30f) {
                                int idx = atomicAdd(&fire_cnt, 1);
                                if (idx < 256) fire_list[idx] = (s << 12) | n;
                            } else if (pr > 1.0e29f) {
                                int idx = atomicAdd(&resc_cnt, 1);
                                if (idx < 64) rescue_list[idx] = (s << 12) | n;
                            }
                        }
                    }
                }
            }
            __syncthreads();
            // rescue / Wf2 never run (counts stay 0)
            {
                xb[sg][r]       += bf2[l * D_ + r];
                xb[sg][r + 256] += bf2[l * D_ + r + 256];
            }
            __syncthreads();
        }

        {
            float x0 = xb[sg][r], x1 = xb[sg][r + 256];
            float s0 = (x0 > lifth[r])       ? 1.0f : 0.0f;
            float s1 = (x1 > lifth[r + 256]) ? 1.0f : 0.0f;
            st0 = s0; st1 = s1;
            size_t so = ((size_t)b * STEPS_ + (t & 63)) * D_;
            scr[(so + r) & SCRMASK_]       = s0;
            scr[(so + r + 256) & SCRMASK_] = s1;
            float rs = s0 * Wr[r] + s1 * Wr[r + 256];
#pragma unroll
            for (int m = 1; m < 64; m <<= 1) rs += __shfl_xor(rs, m);
            if ((r & 63) == 0) red[sg][r >> 6][0] = rs;
            __syncthreads();
            if (r == 0)
                scr[((size_t)b * STEPS_ + (t & 63)) & SCRMASK_] =
                    red[sg][0][0] + red[sg][1][0] + red[sg][2][0] + red[sg][3][0];
        }
        __syncthreads();
    }
    scr[((size_t)b * D_ + r) & SCRMASK_] = st0;
}

// ================= DIAGNOSTIC: stream kernel (full GEMMs, minimal LN/fixed) ====
__global__ __launch_bounds__(1024)
__attribute__((amdgpu_waves_per_eu(4, 4)))
void diag_stream(
    const float* __restrict__ init_state, const float* __restrict__ acts,
    const float* __restrict__ Wa,  const float* __restrict__ ba,
    const float* __restrict__ bf1, const float* __restrict__ bf2,
    const float* __restrict__ lifth, const float* __restrict__ Wr,
    const unsigned* __restrict__ Whi, const unsigned* __restrict__ Wlo,
    const unsigned char* __restrict__ Pf8, const float* __restrict__ bvo,
    float* __restrict__ scr)
{
    __shared__ __align__(16) unsigned afrag[16 * 64 * 4];
    __shared__ __align__(16) unsigned short afrag8[16 * 64 * 4];
    __shared__ __align__(16) float xb[4][D_];
    __shared__ float areg[4][A_];
    __shared__ float red[4][4][2];
    __shared__ int   fire_cnt, resc_cnt;
    __shared__ int   fire_list[256];
    __shared__ int   rescue_list[64];

    const int tid  = threadIdx.x;
    const int sg   = tid >> 8;
    const int r    = tid & 255;
    const int wv   = tid >> 6;
    const int lane = tid & 63;
    const int b    = blockIdx.x * 4 + sg;

    float st0 = init_state[(size_t)b * D_ + r];
    float st1 = init_state[(size_t)b * D_ + r + 256];
#pragma unroll
    for (int z = 0; z < 4; ++z) afrag[tid + z * 1024] = 0;
    ((unsigned*)afrag8)[tid] = 0;
    ((unsigned*)afrag8)[tid + 1024] = 0;
    __syncthreads();

    for (int t = 0; t < DIAG_STEPS_; ++t) {
        if (tid < 128) {
            int sg2 = tid >> 5, j = tid & 31;
            areg[sg2][j] = acts[((size_t)(blockIdx.x * 4 + sg2)) * (STEPS_ * A_) + (t & 63) * A_ + j];
        }
        __syncthreads();
        {
            float x0 = st0 + ba[r];
            float x1 = st1 + ba[r + 256];
#pragma unroll
            for (int j = 0; j < A_; ++j) {
                float av = areg[sg][j];
                x0 += av * Wa[j * D_ + r];
                x1 += av * Wa[j * D_ + r + 256];
            }
            xb[sg][r] = x0; xb[sg][r + 256] = x1;
        }
        __syncthreads();

        for (int l = 0; l < L_; ++l) {
            // minimal LN1: direct pack of xb, ONE barrier, no reduce
            {
                int c = 2 * r;
                float v0 = xb[sg][c], v1 = xb[sg][c + 1];
                unsigned u0 = rne16(v0), u1 = rne16(v1);
                float l0 = v0 - fb(u0), l1 = v1 - fb(u1);
                int kk = c >> 5, grp = (c & 31) >> 3, jp = (c & 7) >> 1;
                afrag[(kk * 64 + ((grp << 4) | sg))       * 4 + jp] = u0 | (u1 << 16);
                afrag[(kk * 64 + ((grp << 4) | (sg + 4))) * 4 + jp] = rne16(l0) | (rne16(l1) << 16);
            }
            __syncthreads();

            // GEMM1 full (verbatim R10)
            {
                const bf16x8* Ah = (const bf16x8*)afrag;
                const size_t lb = (size_t)l * (32 * 16 * 64);
                const bf16x8* BH0 = (const bf16x8*)Whi + lb + (size_t)(2 * wv) * (16 * 64) + lane;
                const bf16x8* BL0 = (const bf16x8*)Wlo + lb + (size_t)(2 * wv) * (16 * 64) + lane;
                const bf16x8* BH1 = BH0 + 16 * 64;
                const bf16x8* BL1 = BL0 + 16 * 64;
                f32x4 c1a = {0.f,0.f,0.f,0.f}, c2a = c1a, c1b = c1a, c2b = c1a;
                bf16x8 aH0, aG0, aH1, aG1;
                bf16x8 bH0, bG0, bH1, bG1;
                bf16x8 cH0, cG0, cH1, cG1;
#define G1LD(S, KK) LD4(S##H0, S##G0, S##H1, S##G1, \
                        BH0 + (KK) * 64, BL0 + (KK) * 64, BH1 + (KK) * 64, BL1 + (KK) * 64)
#define G1MM(S, KK) do { bf16x8 a_ = Ah[(KK) * 64 + lane]; \
    c1a = MFMA16(a_, S##H0, c1a); c2a = MFMA16(a_, S##G0, c2a); \
    c1b = MFMA16(a_, S##H1, c1b); c2b = MFMA16(a_, S##G1, c2b); } while (0)
#define G1W(N, S) WAIT4(N, S##H0, S##G0, S##H1, S##G1)
                G1LD(a, 0); G1LD(b, 1); G1LD(c, 2);
                G1W(8, a); G1MM(a, 0);  G1LD(a, 3);
                G1W(8, b); G1MM(b, 1);  G1LD(b, 4);
                G1W(8, c); G1MM(c, 2);  G1LD(c, 5);
                G1W(8, a); G1MM(a, 3);  G1LD(a, 6);
                G1W(8, b); G1MM(b, 4);  G1LD(b, 7);
                G1W(8, c); G1MM(c, 5);  G1LD(c, 8);
                G1W(8, a); G1MM(a, 6);  G1LD(a, 9);
                G1W(8, b); G1MM(b, 7);  G1LD(b, 10);
                G1W(8, c); G1MM(c, 8);  G1LD(c, 11);
                G1W(8, a); G1MM(a, 9);  G1LD(a, 12);
                G1W(8, b); G1MM(b, 10); G1LD(b, 13);
                G1W(8, c); G1MM(c, 11); G1LD(c, 14);
                G1W(8, a); G1MM(a, 12); G1LD(a, 15);
                G1W(8, b); G1MM(b, 13);
                G1W(4, c); G1MM(c, 14);
                G1W(0, a); G1MM(a, 15);
#undef G1LD
#undef G1MM
#undef G1W
                const int nt0 = 2 * wv, nt1 = nt0 + 1;
#pragma unroll
                for (int s = 0; s < 4; ++s) {
                    float pa = c1a[s] + c2a[s]; float qa = __shfl(pa, (lane & 15) + 16);
                    float pb = c1b[s] + c2b[s]; float qb = __shfl(pb, (lane & 15) + 16);
                    if (lane < 16) {
                        int ca = nt0 * 16 + lane, cb = nt1 * 16 + lane;
                        xb[s][ca] += pa + qa + bvo[l * D_ + ca];
                        xb[s][cb] += pb + qb + bvo[l * D_ + cb];
                    }
                }
            }
            __syncthreads();

            if (tid == 0) { fire_cnt = 0; resc_cnt = 0; }

            // minimal LN2: direct fp8 pack, ONE barrier
            {
                int c = 2 * r;
                unsigned u = __builtin_amdgcn_cvt_pk_fp8_f32(xb[sg][c], xb[sg][c + 1], 0, false);
                int kk = c >> 5, grp = (c & 31) >> 3, j = c & 7;
                afrag8[(kk * 64 + ((grp << 4) | sg)) * 4 + (j >> 1)] = (unsigned short)u;
            }
            __syncthreads();

            // GEMM2 full (verbatim R10), neutered thresholds
            {
                const unsigned long* Ah8 = (const unsigned long*)afrag8;
                const int m0 = 4 * wv;
                const u64x2* Q0 = (const u64x2*)Pf8 + ((size_t)(l * 64 + m0 + 0) * 8) * 64 + lane;
                const u64x2* Q1 = (const u64x2*)Pf8 + ((size_t)(l * 64 + m0 + 1) * 8) * 64 + lane;
                const u64x2* Q2 = (const u64x2*)Pf8 + ((size_t)(l * 64 + m0 + 2) * 8) * 64 + lane;
                const u64x2* Q3 = (const u64x2*)Pf8 + ((size_t)(l * 64 + m0 + 3) * 8) * 64 + lane;
                f32x4 p0 = {0.f,0.f,0.f,0.f}, p1 = p0, p2 = p0, p3 = p0;
                u64x2 aB0, aB1, aB2, aB3;
                u64x2 bB0, bB1, bB2, bB3;
                u64x2 cB0, cB1, cB2, cB3;
#define G2LD(S, P) LD4(S##B0, S##B1, S##B2, S##B3, \
                       Q0 + (P) * 64, Q1 + (P) * 64, Q2 + (P) * 64, Q3 + (P) * 64)
#define G2MM(S, P) do { \
    unsigned long a0_ = Ah8[(2 * (P))     * 64 + lane]; \
    unsigned long a1_ = Ah8[(2 * (P) + 1) * 64 + lane]; \
    p0 = MFMA8(a0_, S##B0.x, p0); p1 = MFMA8(a0_, S##B1.x, p1); \
    p2 = MFMA8(a0_, S##B2.x, p2); p3 = MFMA8(a0_, S##B3.x, p3); \
    p0 = MFMA8(a1_, S##B0.y, p0); p1 = MFMA8(a1_, S##B1.y, p1); \
    p2 = MFMA8(a1_, S##B2.y, p2); p3 = MFMA8(a1_, S##B3.y, p3); } while (0)
#define G2W(N, S) WAIT4(N, S##B0, S##B1, S##B2, S##B3)
                G2LD(a, 0); G2LD(b, 1); G2LD(c, 2);
                G2W(8, a); G2MM(a, 0); G2LD(a, 3);
                G2W(8, b); G2MM(b, 1); G2LD(b, 4);
                G2W(8, c); G2MM(c, 2); G2LD(c, 5);
                G2W(8, a); G2MM(a, 3); G2LD(a, 6);
                G2W(8, b); G2MM(b, 4); G2LD(b, 7);
                G2W(8, c); G2MM(c, 5);
                G2W(4, a); G2MM(a, 6);
                G2W(0, b); G2MM(b, 7);
#undef G2LD
#undef G2MM
#undef G2W
                const float* bf1g = bf1 + l * FF_;
#pragma unroll
                for (int s = 0; s < 4; ++s) {
                    float v0 = p0[s]; float w0 = __shfl(v0, (lane & 15) + 16);
                    float v1 = p1[s]; float w1 = __shfl(v1, (lane & 15) + 16);
                    float v2 = p2[s]; float w2 = __shfl(v2, (lane & 15) + 16);
                    float v3 = p3[s]; float w3 = __shfl(v3, (lane & 15) + 16);
                    if (lane < 16) {
#pragma unroll
                        for (int q = 0; q < 4; ++q) {
                            float sum = (q == 0) ? v0 + w0 : (q == 1) ? v1 + w1
                                       : (q == 2) ? v2 + w2 : v3 + w3;
                            int n = (m0 + q) * 16 + lane;
                            float pr = sum * 0.0625f + bf1g[n] - 2.0f;
                            if (pr > 1.0e30f) {
                                int idx = atomicAdd(&fire_cnt, 1);
                                if (idx < 256) fire_list[idx] = (s << 12) | n;
                            } else if (pr > 1.0e29f) {
                                int idx = atomicAdd(&resc_cnt, 1);
                                if (idx < 64) rescue_list[idx] = (s << 12) | n;
                            }
                        }
                    }
                }
            }
            __syncthreads();
            {
                xb[sg][r]       += bf2[l * D_ + r];
                xb[sg][r + 256] += bf2[l * D_ + r + 256];
            }
            __syncthreads();
        }

        {
            float x0 = xb[sg][r], x1 = xb[sg][r + 256];
            float s0 = (x0 > lifth[r])       ? 1.0f : 0.0f;
            float s1 = (x1 > lifth[r + 256]) ? 1.0f : 0.0f;
            st0 = s0; st1 = s1;
            size_t so = ((size_t)b * STEPS_ + (t & 63)) * D_;
            scr[(so + r) & SCRMASK_]       = s0;
            scr[(so + r + 256) & SCRMASK_] = s1;
            float rs = s0 * Wr[r] + s1 * Wr[r + 256];
#pragma unroll
            for (int m = 1; m < 64; m <<= 1) rs += __shfl_xor(rs, m);
            if ((r & 63) == 0) red[sg][r >> 6][0] = rs;
            __syncthreads();
            if (r == 0)
                scr[((size_t)b * STEPS_ + (t & 63)) & SCRMASK_] =
                    red[sg][0][0] + red[sg][1][0] + red[sg][2][0] + red[sg][3][0];
        }
        __syncthreads();
    }
    scr[((size_t)b * D_ + r) & SCRMASK_] = st0;
}

extern "C" void kernel_launch(void* const* d_in, const int* in_sizes, int n_in,
                              void* d_out, int out_size, void* d_ws, size_t ws_size,
                              hipStream_t stream) {
    (void)in_sizes; (void)n_in; (void)out_size; (void)ws_size;
    const float* init_state = (const float*)d_in[0];
    const float* acts  = (const float*)d_in[1];
    const float* Wa    = (const float*)d_in[2];
    const float* ba    = (const float*)d_in[3];
    const float* ln1g  = (const float*)d_in[4];
    const float* ln1b  = (const float*)d_in[5];
    // d_in[6..9] = Wq, bq, Wk, bk: dead (softmax over length-1 axis == 1)
    const float* Wv    = (const float*)d_in[10];
    const float* bv    = (const float*)d_in[11];
    const float* Wo    = (const float*)d_in[12];
    const float* bo    = (const float*)d_in[13];
    const float* ln2g  = (const float*)d_in[14];
    const float* ln2b  = (const float*)d_in[15];
    const float* Wf1   = (const float*)d_in[16];
    const float* bf1   = (const float*)d_in[17];
    const float* Wf2   = (const float*)d_in[18];
    const float* bf2   = (const float*)d_in[19];
    const float* lifth = (const float*)d_in[20];
    const float* Wr    = (const float*)d_in[21];
    const float* br    = (const float*)d_in[22];

    // ws: Whi(2MB) | Wlo(2MB) | Pf8(2MB) | bvo(8KB) | scr(1MB)
    unsigned* Whi = (unsigned*)d_ws;
    unsigned* Wlo = Whi + 524288;
    unsigned char* Pf8 = (unsigned char*)(Wlo + 524288);
    float*    bvo = (float*)(Pf8 + 2097152);
    float*    scr = bvo + 2048;

    float* out         = (float*)d_out;
    float* out_states  = out;
    float* out_rewards = out + (size_t)B_ * STEPS_ * D_;
    float* out_final   = out_rewards + (size_t)B_ * STEPS_;

    wvo_kernel<<<dim3(256), dim3(256), 0, stream>>>(Wv, Wo, Whi, Wlo);
    bvo_kernel<<<dim3(8),   dim3(256), 0, stream>>>(bv, bo, Wo, bvo);
    packwf1_fp8<<<dim3(2048), dim3(64), 0, stream>>>(Wf1, Pf8);
    smain<<<dim3(256), dim3(1024), 0, stream>>>(
        init_state, acts, Wa, ba, ln1g, ln1b, ln2g, ln2b,
        Wf1, bf1, Wf2, bf2, lifth, Wr, br, Whi, Wlo, Pf8, bvo,
        out_states, out_rewards, out_final);
    diag_fixed<<<dim3(256), dim3(1024), 0, stream>>>(
        init_state, acts, Wa, ba, ln1g, ln1b, ln2g, ln2b,
        bf1, bf2, lifth, Wr, bvo, scr);
    diag_stream<<<dim3(256), dim3(1024), 0, stream>>>(
        init_state, acts, Wa, ba, bf1, bf2, lifth, Wr,
        Whi, Wlo, Pf8, bvo, scr);
}

// Round 14
// 6439.874 us; speedup vs baseline: 6.3162x; 6.3162x over previous
//
#include <hip/hip_runtime.h>

#define D_ 512
#define FF_ 1024
#define L_ 4
#define A_ 32
#define B_ 1024
#define STEPS_ 64
#define RB8_ 0.15f    // fp8 GEMM2 rescue band: >=5 sigma

typedef __attribute__((ext_vector_type(8))) short bf16x8;
typedef __attribute__((ext_vector_type(4))) float f32x4;
typedef __attribute__((ext_vector_type(2))) unsigned long u64x2;
#define MFMA16(a,b,c) __builtin_amdgcn_mfma_f32_16x16x32_bf16(a,b,c,0,0,0)
#define MFMA8(a,b,c)  __builtin_amdgcn_mfma_f32_16x16x32_fp8_fp8((long)(a),(long)(b),(c),0,0,0)

__device__ __forceinline__ unsigned rne16(float f) {
    unsigned u = __float_as_uint(f);
    return (u + 0x7fffu + ((u >> 16) & 1u)) >> 16;
}
__device__ __forceinline__ float fb(unsigned hu) { return __uint_as_float(hu << 16); }

// ---- asm load/wait primitives (R9/R10-verified) ------------------------------
#define LD4(R0, R1, R2, R3, P0_, P1_, P2_, P3_)                                \
    asm volatile("global_load_dwordx4 %0, %4, off\n\t"                         \
                 "global_load_dwordx4 %1, %5, off\n\t"                         \
                 "global_load_dwordx4 %2, %6, off\n\t"                         \
                 "global_load_dwordx4 %3, %7, off"                             \
                 : "=&v"(R0), "=&v"(R1), "=&v"(R2), "=&v"(R3)                  \
                 : "v"(P0_), "v"(P1_), "v"(P2_), "v"(P3_))

#define WAIT4(N, R0, R1, R2, R3)                                               \
    asm volatile("s_waitcnt vmcnt(" #N ")"                                     \
                 : "+v"(R0), "+v"(R1), "+v"(R2), "+v"(R3) :: "memory")

// ---------------- Wvo[l] = Wv[l] @ Wo[l], split-bf16 MFMA fragments ------------
__global__ __launch_bounds__(256) void wvo_kernel(
    const float* __restrict__ Wv, const float* __restrict__ Wo,
    unsigned* __restrict__ Whi, unsigned* __restrict__ Wlo)
{
    __shared__ float wvt[16][D_];
    int bx  = blockIdx.x;
    int l   = bx >> 6;
    int rem = bx & 63;
    int k0  = (rem >> 1) * 16;
    int n   = (rem & 1) * 256 + threadIdx.x;

    const float* wvbase = Wv + (size_t)l * D_ * D_ + (size_t)k0 * D_;
    for (int idx = threadIdx.x; idx < 16 * D_; idx += 256)
        wvt[idx >> 9][idx & (D_ - 1)] = wvbase[idx];
    __syncthreads();

    float acc[16];
#pragma unroll
    for (int kk = 0; kk < 16; ++kk) acc[kk] = 0.f;

    const float* wop = Wo + (size_t)l * D_ * D_ + n;
    for (int m = 0; m < D_; m += 4) {
        float w0 = wop[(m + 0) * D_];
        float w1 = wop[(m + 1) * D_];
        float w2 = wop[(m + 2) * D_];
        float w3 = wop[(m + 3) * D_];
#pragma unroll
        for (int kk = 0; kk < 16; ++kk) {
            float4 wv4 = *(const float4*)&wvt[kk][m];
            acc[kk] += wv4.x * w0 + wv4.y * w1 + wv4.z * w2 + wv4.w * w3;
        }
    }
    int nt = n >> 4, ln15 = n & 15;
    int kkblk = k0 >> 5;
    int gbase = (k0 & 31) >> 3;
#pragma unroll
    for (int gi = 0; gi < 2; ++gi) {
        int lane_s = ((gbase + gi) << 4) | ln15;
        size_t fbase = ((((size_t)l * 32 + nt) * 16 + kkblk) * 64 + lane_s) * 4;
#pragma unroll
        for (int jp = 0; jp < 4; ++jp) {
            float v0 = acc[gi * 8 + jp * 2], v1 = acc[gi * 8 + jp * 2 + 1];
            unsigned h0 = rne16(v0), h1 = rne16(v1);
            Whi[fbase + jp] = h0 | (h1 << 16);
            float r0 = v0 - fb(h0), r1 = v1 - fb(h1);
            Wlo[fbase + jp] = rne16(r0) | (rne16(r1) << 16);
        }
    }
}

// ---------------- bvo[l] = bv[l] @ Wo[l] + bo[l] -------------------------------
__global__ __launch_bounds__(256) void bvo_kernel(
    const float* __restrict__ bv, const float* __restrict__ bo,
    const float* __restrict__ Wo, float* __restrict__ bvo)
{
    int l = blockIdx.x >> 1;
    int n = (blockIdx.x & 1) * 256 + threadIdx.x;
    float acc = bo[l * D_ + n];
    const float* wop = Wo + (size_t)l * D_ * D_ + n;
    const float* bvp = bv + l * D_;
    for (int m = 0; m < D_; ++m) acc += bvp[m] * wop[m * D_];
    bvo[l * D_ + n] = acc;
}

// ---------------- Wf1 -> fp8 e4m3 MFMA fragments, x16 scaled, kk-pair packed ----
__global__ __launch_bounds__(64) void packwf1_fp8(
    const float* __restrict__ Wf1, unsigned char* __restrict__ Pf8)
{
    int bid = blockIdx.x;              // 4*64*8 = 2048
    int lane = threadIdx.x;
    int l  = bid >> 9;
    int nt = (bid >> 3) & 63;
    int p  = bid & 7;
    int n  = nt * 16 + (lane & 15);
    unsigned w[4];
#pragma unroll
    for (int half = 0; half < 2; ++half) {
        int kk = 2 * p + half;
        int krow = kk * 32 + (lane >> 4) * 8;
        const float* src = Wf1 + ((size_t)l * D_ + krow) * FF_ + n;
        float f0 = src[0 * FF_] * 16.f, f1 = src[1 * FF_] * 16.f;
        float f2 = src[2 * FF_] * 16.f, f3 = src[3 * FF_] * 16.f;
        float f4 = src[4 * FF_] * 16.f, f5 = src[5 * FF_] * 16.f;
        float f6 = src[6 * FF_] * 16.f, f7 = src[7 * FF_] * 16.f;
        unsigned lo = 0, hi = 0;
        lo = __builtin_amdgcn_cvt_pk_fp8_f32(f0, f1, lo, false);
        lo = __builtin_amdgcn_cvt_pk_fp8_f32(f2, f3, lo, true);
        hi = __builtin_amdgcn_cvt_pk_fp8_f32(f4, f5, hi, false);
        hi = __builtin_amdgcn_cvt_pk_fp8_f32(f6, f7, hi, true);
        w[half * 2] = lo; w[half * 2 + 1] = hi;
    }
    uint4 o; o.x = w[0]; o.y = w[1]; o.z = w[2]; o.w = w[3];
    ((uint4*)Pf8)[((size_t)(l * 64 + nt) * 8 + p) * 64 + lane] = o;
}

// ---------------- LN1: xb -> bf16 A-fragments (R3-verified) --------------------
__device__ __forceinline__ void layer_norm_frag(
    float (*xb)[D_], unsigned* __restrict__ afrag,
    const float* __restrict__ g, const float* __restrict__ bt,
    float (*red)[4][2], int sg, int r)
{
    int c = 2 * r;
    float v0 = xb[sg][c], v1 = xb[sg][c + 1];
    float s  = v0 + v1;
    float ss = v0 * v0 + v1 * v1;
#pragma unroll
    for (int m = 1; m < 64; m <<= 1) {
        s  += __shfl_xor(s, m);
        ss += __shfl_xor(ss, m);
    }
    if ((r & 63) == 0) { red[sg][r >> 6][0] = s; red[sg][r >> 6][1] = ss; }
    __syncthreads();
    float S  = red[sg][0][0] + red[sg][1][0] + red[sg][2][0] + red[sg][3][0];
    float SS = red[sg][0][1] + red[sg][1][1] + red[sg][2][1] + red[sg][3][1];
    float mean = S * (1.f / 512.f);
    float var  = SS * (1.f / 512.f) - mean * mean;
    float rstd = 1.0f / sqrtf(var + 1e-5f);
    float h0 = (v0 - mean) * rstd * g[c]     + bt[c];
    float h1 = (v1 - mean) * rstd * g[c + 1] + bt[c + 1];
    unsigned u0 = rne16(h0), u1 = rne16(h1);
    float l0 = h0 - fb(u0), l1 = h1 - fb(u1);
    int kk = c >> 5, grp = (c & 31) >> 3, jp = (c & 7) >> 1;
    afrag[(kk * 64 + ((grp << 4) | sg))       * 4 + jp] = u0 | (u1 << 16);
    afrag[(kk * 64 + ((grp << 4) | (sg + 4))) * 4 + jp] = rne16(l0) | (rne16(l1) << 16);
    __syncthreads();
}

// ---------------- LN2: xb -> fp8 A-fragments; saves mean/rstd for rescue -------
__device__ __forceinline__ void ln2_pack8(
    float (*xb)[D_], unsigned short* __restrict__ afrag8,
    const float* __restrict__ g, const float* __restrict__ bt,
    float (*red)[4][2], float* __restrict__ ln2m, float* __restrict__ ln2r,
    int sg, int r)
{
    int c = 2 * r;
    float v0 = xb[sg][c], v1 = xb[sg][c + 1];
    float s  = v0 + v1;
    float ss = v0 * v0 + v1 * v1;
#pragma unroll
    for (int m = 1; m < 64; m <<= 1) {
        s  += __shfl_xor(s, m);
        ss += __shfl_xor(ss, m);
    }
    if ((r & 63) == 0) { red[sg][r >> 6][0] = s; red[sg][r >> 6][1] = ss; }
    __syncthreads();
    float S  = red[sg][0][0] + red[sg][1][0] + red[sg][2][0] + red[sg][3][0];
    float SS = red[sg][0][1] + red[sg][1][1] + red[sg][2][1] + red[sg][3][1];
    float mean = S * (1.f / 512.f);
    float var  = SS * (1.f / 512.f) - mean * mean;
    float rstd = 1.0f / sqrtf(var + 1e-5f);
    if (r == 0) { ln2m[sg] = mean; ln2r[sg] = rstd; }
    float h0 = (v0 - mean) * rstd * g[c]     + bt[c];
    float h1 = (v1 - mean) * rstd * g[c + 1] + bt[c + 1];
    unsigned u = __builtin_amdgcn_cvt_pk_fp8_f32(h0, h1, 0, false);
    int kk = c >> 5, grp = (c & 31) >> 3, j = c & 7;
    afrag8[(kk * 64 + ((grp << 4) | sg)) * 4 + (j >> 1)] = (unsigned short)u;
    __syncthreads();
}

// ---------------- persistent recurrence kernel (R10 + per-WG kk rotation) ------
__global__ __launch_bounds__(1024)
__attribute__((amdgpu_waves_per_eu(4, 4)))
void smain(
    const float* __restrict__ init_state,
    const float* __restrict__ acts,
    const float* __restrict__ Wa,  const float* __restrict__ ba,
    const float* __restrict__ ln1g, const float* __restrict__ ln1b,
    const float* __restrict__ ln2g, const float* __restrict__ ln2b,
    const float* __restrict__ Wf1, const float* __restrict__ bf1,
    const float* __restrict__ Wf2, const float* __restrict__ bf2,
    const float* __restrict__ lifth,
    const float* __restrict__ Wr,  const float* __restrict__ br,
    const unsigned* __restrict__ Whi, const unsigned* __restrict__ Wlo,
    const unsigned char* __restrict__ Pf8, const float* __restrict__ bvo,
    float* __restrict__ out_states, float* __restrict__ out_rewards,
    float* __restrict__ out_final)
{
    __shared__ __align__(16) unsigned afrag[16 * 64 * 4];
    __shared__ __align__(16) unsigned short afrag8[16 * 64 * 4];
    __shared__ __align__(16) float xb[4][D_];
    __shared__ float areg[4][A_];
    __shared__ float red[4][4][2];
    __shared__ float rr[16];
    __shared__ float ln2m[4], ln2r[4];
    __shared__ int   fire_cnt, resc_cnt;
    __shared__ int   fire_list[256];
    __shared__ int   rescue_list[64];

    const int tid  = threadIdx.x;
    const int sg   = tid >> 8;
    const int r    = tid & 255;
    const int wv   = tid >> 6;
    const int lane = tid & 63;
    const int b    = blockIdx.x * 4 + sg;
    // kk-sweep stagger: co-XCD WGs (blockIdx = xcd + 8k) get distinct offsets,
    // spreading the instantaneous L2 working window over the full weight set.
    const int wgo1 = (blockIdx.x >> 3) & 15;   // GEMM1: 16 kk phases
    const int wgo2 = (blockIdx.x >> 3) & 7;    // GEMM2: 8 kk-pair phases
#define RK1(P) (((P) + wgo1) & 15)
#define RK2(P) (((P) + wgo2) & 7)

    float st0 = init_state[(size_t)b * D_ + r];
    float st1 = init_state[(size_t)b * D_ + r + 256];
#pragma unroll
    for (int z = 0; z < 4; ++z) afrag[tid + z * 1024] = 0;
    ((unsigned*)afrag8)[tid] = 0;
    ((unsigned*)afrag8)[tid + 1024] = 0;
    __syncthreads();

    for (int t = 0; t < STEPS_; ++t) {
        if (tid < 128) {
            int sg2 = tid >> 5, j = tid & 31;
            areg[sg2][j] = acts[((size_t)(blockIdx.x * 4 + sg2)) * (STEPS_ * A_) + t * A_ + j];
        }
        __syncthreads();

        // ---- x = state + a @ Wa + ba ----
        {
            float x0 = st0 + ba[r];
            float x1 = st1 + ba[r + 256];
#pragma unroll
            for (int j = 0; j < A_; ++j) {
                float av = areg[sg][j];
                x0 += av * Wa[j * D_ + r];
                x1 += av * Wa[j * D_ + r + 256];
            }
            xb[sg][r] = x0; xb[sg][r + 256] = x1;
        }
        __syncthreads();

        for (int l = 0; l < L_; ++l) {
            // ---- LN1: xb -> afrag (bf16 hi/lo) ----
            layer_norm_frag(xb, afrag, ln1g + l * D_, ln1b + l * D_, red, sg, r);

            // ---- GEMM1 (split-bf16, asm pipeline, rotated kk order) ----
            {
                const bf16x8* Ah = (const bf16x8*)afrag;
                const size_t lb = (size_t)l * (32 * 16 * 64);
                const bf16x8* BH0 = (const bf16x8*)Whi + lb + (size_t)(2 * wv) * (16 * 64) + lane;
                const bf16x8* BL0 = (const bf16x8*)Wlo + lb + (size_t)(2 * wv) * (16 * 64) + lane;
                const bf16x8* BH1 = BH0 + 16 * 64;
                const bf16x8* BL1 = BL0 + 16 * 64;
                f32x4 c1a = {0.f,0.f,0.f,0.f}, c2a = c1a, c1b = c1a, c2b = c1a;
                bf16x8 aH0, aG0, aH1, aG1;
                bf16x8 bH0, bG0, bH1, bG1;
                bf16x8 cH0, cG0, cH1, cG1;
#define G1LD(S, KK) LD4(S##H0, S##G0, S##H1, S##G1, \
                        BH0 + RK1(KK) * 64, BL0 + RK1(KK) * 64, \
                        BH1 + RK1(KK) * 64, BL1 + RK1(KK) * 64)
#define G1MM(S, KK) do { bf16x8 a_ = Ah[RK1(KK) * 64 + lane]; \
    c1a = MFMA16(a_, S##H0, c1a); c2a = MFMA16(a_, S##G0, c2a); \
    c1b = MFMA16(a_, S##H1, c1b); c2b = MFMA16(a_, S##G1, c2b); } while (0)
#define G1W(N, S) WAIT4(N, S##H0, S##G0, S##H1, S##G1)
                G1LD(a, 0); G1LD(b, 1); G1LD(c, 2);
                G1W(8, a); G1MM(a, 0);  G1LD(a, 3);
                G1W(8, b); G1MM(b, 1);  G1LD(b, 4);
                G1W(8, c); G1MM(c, 2);  G1LD(c, 5);
                G1W(8, a); G1MM(a, 3);  G1LD(a, 6);
                G1W(8, b); G1MM(b, 4);  G1LD(b, 7);
                G1W(8, c); G1MM(c, 5);  G1LD(c, 8);
                G1W(8, a); G1MM(a, 6);  G1LD(a, 9);
                G1W(8, b); G1MM(b, 7);  G1LD(b, 10);
                G1W(8, c); G1MM(c, 8);  G1LD(c, 11);
                G1W(8, a); G1MM(a, 9);  G1LD(a, 12);
                G1W(8, b); G1MM(b, 10); G1LD(b, 13);
                G1W(8, c); G1MM(c, 11); G1LD(c, 14);
                G1W(8, a); G1MM(a, 12); G1LD(a, 15);
                G1W(8, b); G1MM(b, 13);
                G1W(4, c); G1MM(c, 14);
                G1W(0, a); G1MM(a, 15);
#undef G1LD
#undef G1MM
#undef G1W
                const int nt0 = 2 * wv, nt1 = nt0 + 1;
#pragma unroll
                for (int s = 0; s < 4; ++s) {
                    float pa = c1a[s] + c2a[s]; float qa = __shfl(pa, (lane & 15) + 16);
                    float pb = c1b[s] + c2b[s]; float qb = __shfl(pb, (lane & 15) + 16);
                    if (lane < 16) {
                        int ca = nt0 * 16 + lane, cb = nt1 * 16 + lane;
                        xb[s][ca] += pa + qa + bvo[l * D_ + ca];
                        xb[s][cb] += pb + qb + bvo[l * D_ + cb];
                    }
                }
            }
            __syncthreads();

            if (tid == 0) { fire_cnt = 0; resc_cnt = 0; }

            // ---- LN2: xb -> afrag8 (fp8), save mean/rstd ----
            ln2_pack8(xb, afrag8, ln2g + l * D_, ln2b + l * D_, red, ln2m, ln2r, sg, r);

            // ---- GEMM2 (fp8 pair-packed, rotated kk-pair order) ----
            {
                const unsigned long* Ah8 = (const unsigned long*)afrag8;
                const int m0 = 4 * wv;
                const u64x2* Q0 = (const u64x2*)Pf8 + ((size_t)(l * 64 + m0 + 0) * 8) * 64 + lane;
                const u64x2* Q1 = (const u64x2*)Pf8 + ((size_t)(l * 64 + m0 + 1) * 8) * 64 + lane;
                const u64x2* Q2 = (const u64x2*)Pf8 + ((size_t)(l * 64 + m0 + 2) * 8) * 64 + lane;
                const u64x2* Q3 = (const u64x2*)Pf8 + ((size_t)(l * 64 + m0 + 3) * 8) * 64 + lane;
                f32x4 p0 = {0.f,0.f,0.f,0.f}, p1 = p0, p2 = p0, p3 = p0;
                u64x2 aB0, aB1, aB2, aB3;
                u64x2 bB0, bB1, bB2, bB3;
                u64x2 cB0, cB1, cB2, cB3;
#define G2LD(S, P) LD4(S##B0, S##B1, S##B2, S##B3, \
                       Q0 + RK2(P) * 64, Q1 + RK2(P) * 64, \
                       Q2 + RK2(P) * 64, Q3 + RK2(P) * 64)
#define G2MM(S, P) do { \
    unsigned long a0_ = Ah8[(2 * RK2(P))     * 64 + lane]; \
    unsigned long a1_ = Ah8[(2 * RK2(P) + 1) * 64 + lane]; \
    p0 = MFMA8(a0_, S##B0.x, p0); p1 = MFMA8(a0_, S##B1.x, p1); \
    p2 = MFMA8(a0_, S##B2.x, p2); p3 = MFMA8(a0_, S##B3.x, p3); \
    p0 = MFMA8(a1_, S##B0.y, p0); p1 = MFMA8(a1_, S##B1.y, p1); \
    p2 = MFMA8(a1_, S##B2.y, p2); p3 = MFMA8(a1_, S##B3.y, p3); } while (0)
#define G2W(N, S) WAIT4(N, S##B0, S##B1, S##B2, S##B3)
                G2LD(a, 0); G2LD(b, 1); G2LD(c, 2);
                G2W(8, a); G2MM(a, 0); G2LD(a, 3);
                G2W(8, b); G2MM(b, 1); G2LD(b, 4);
                G2W(8, c); G2MM(c, 2); G2LD(c, 5);
                G2W(8, a); G2MM(a, 3); G2LD(a, 6);
                G2W(8, b); G2MM(b, 4); G2LD(b, 7);
                G2W(8, c); G2MM(c, 5);
                G2W(4, a); G2MM(a, 6);
                G2W(0, b); G2MM(b, 7);
#undef G2LD
#undef G2MM
#undef G2W
                const float* bf1g = bf1 + l * FF_;
#pragma unroll
                for (int s = 0; s < 4; ++s) {
                    float v0 = p0[s]; float w0 = __shfl(v0, (lane & 15) + 16);
                    float v1 = p1[s]; float w1 = __shfl(v1, (lane & 15) + 16);
                    float v2 = p2[s]; float w2 = __shfl(v2, (lane & 15) + 16);
                    float v3 = p3[s]; float w3 = __shfl(v3, (lane & 15) + 16);
                    if (lane < 16) {
#pragma unroll
                        for (int q = 0; q < 4; ++q) {
                            float sum = (q == 0) ? v0 + w0 : (q == 1) ? v1 + w1
                                       : (q == 2) ? v2 + w2 : v3 + w3;
                            int n = (m0 + q) * 16 + lane;
                            float pr = sum * 0.0625f + bf1g[n] - 2.0f;
                            if (pr > RB8_) {
                                int idx = atomicAdd(&fire_cnt, 1);
                                if (idx < 256) fire_list[idx] = (s << 12) | n;
                            } else if (pr > -RB8_) {
                                int idx = atomicAdd(&resc_cnt, 1);
                                if (idx < 64) rescue_list[idx] = (s << 12) | n;
                            }
                        }
                    }
                }
            }
            __syncthreads();

            // ---- rescue: full fp32 recompute (h2 from xb + saved mean/rstd) ----
            {
                int rc = resc_cnt; if (rc > 64) rc = 64;
                const float* g2 = ln2g + l * D_;
                const float* b2 = ln2b + l * D_;
                for (int e = 0; e < rc; ++e) {
                    int ent = rescue_list[e];
                    int i = ent >> 12, n = ent & 4095;
                    float p = 0.f;
                    if (tid < D_) {
                        float hh = (xb[i][tid] - ln2m[i]) * ln2r[i] * g2[tid] + b2[tid];
                        p = hh * Wf1[((size_t)l * D_ + tid) * FF_ + n];
                    }
#pragma unroll
                    for (int m = 1; m < 64; m <<= 1) p += __shfl_xor(p, m);
                    if ((tid & 63) == 0) rr[tid >> 6] = p;
                    __syncthreads();
                    if (tid == 0) {
                        float dot = 0.f;
#pragma unroll
                        for (int w = 0; w < 8; ++w) dot += rr[w];
                        float pre = dot + bf1[l * FF_ + n] - 2.0f;
                        if (pre > 0.f) {
                            int idx = atomicAdd(&fire_cnt, 1);
                            if (idx < 256) fire_list[idx] = ent;
                        }
                    }
                    __syncthreads();
                }
            }

            // ---- sparse s @ Wf2 + bf2 ----
            {
                int cnt = fire_cnt; if (cnt > 256) cnt = 256;
                if (cnt > 0) {
                    for (int e = 0; e < cnt; ++e) {
                        int ent = fire_list[e];
                        int i = ent >> 12, n = ent & 4095;
                        if (tid < D_) xb[i][tid] += Wf2[(size_t)l * (FF_ * D_) + (size_t)n * D_ + tid];
                    }
                    __syncthreads();
                }
                xb[sg][r]       += bf2[l * D_ + r];
                xb[sg][r + 256] += bf2[l * D_ + r + 256];
            }
            __syncthreads();
        } // layers

        // ---- LIF spike, outputs (nontemporal), reward ----
        {
            float x0 = xb[sg][r], x1 = xb[sg][r + 256];
            float s0 = (x0 > lifth[r])       ? 1.0f : 0.0f;
            float s1 = (x1 > lifth[r + 256]) ? 1.0f : 0.0f;
            st0 = s0; st1 = s1;
            size_t so = ((size_t)b * STEPS_ + t) * D_;
            __builtin_nontemporal_store(s0, &out_states[so + r]);
            __builtin_nontemporal_store(s1, &out_states[so + r + 256]);

            float rs = s0 * Wr[r] + s1 * Wr[r + 256];
#pragma unroll
            for (int m = 1; m < 64; m <<= 1) rs += __shfl_xor(rs, m);
            if ((r & 63) == 0) red[sg][r >> 6][0] = rs;
            __syncthreads();
            if (r == 0)
                __builtin_nontemporal_store(
                    red[sg][0][0] + red[sg][1][0] + red[sg][2][0] + red[sg][3][0] + br[0],
                    &out_rewards[(size_t)b * STEPS_ + t]);
        }
        __syncthreads();
    } // steps

    __builtin_nontemporal_store(st0, &out_final[(size_t)b * D_ + r]);
    __builtin_nontemporal_store(st1, &out_final[(size_t)b * D_ + r + 256]);
#undef RK1
#undef RK2
}

extern "C" void kernel_launch(void* const* d_in, const int* in_sizes, int n_in,
                              void* d_out, int out_size, void* d_ws, size_t ws_size,
                              hipStream_t stream) {
    (void)in_sizes; (void)n_in; (void)out_size; (void)ws_size;
    const float* init_state = (const float*)d_in[0];
    const float* acts  = (const float*)d_in[1];
    const float* Wa    = (const float*)d_in[2];
    const float* ba    = (const float*)d_in[3];
    const float* ln1g  = (const float*)d_in[4];
    const float* ln1b  = (const float*)d_in[5];
    // d_in[6..9] = Wq, bq, Wk, bk: dead (softmax over length-1 axis == 1)
    const float* Wv    = (const float*)d_in[10];
    const float* bv    = (const float*)d_in[11];
    const float* Wo    = (const float*)d_in[12];
    const float* bo    = (const float*)d_in[13];
    const float* ln2g  = (const float*)d_in[14];
    const float* ln2b  = (const float*)d_in[15];
    const float* Wf1   = (const float*)d_in[16];
    const float* bf1   = (const float*)d_in[17];
    const float* Wf2   = (const float*)d_in[18];
    const float* bf2   = (const float*)d_in[19];
    const float* lifth = (const float*)d_in[20];
    const float* Wr    = (const float*)d_in[21];
    const float* br    = (const float*)d_in[22];

    // ws: Whi(2MB) | Wlo(2MB) | Pf8(2MB) | bvo(8KB)
    unsigned* Whi = (unsigned*)d_ws;
    unsigned* Wlo = Whi + 524288;
    unsigned char* Pf8 = (unsigned char*)(Wlo + 524288);
    float*    bvo = (float*)(Pf8 + 2097152);

    float* out         = (float*)d_out;
    float* out_states  = out;
    float* out_rewards = out + (size_t)B_ * STEPS_ * D_;
    float* out_final   = out_rewards + (size_t)B_ * STEPS_;

    wvo_kernel<<<dim3(256), dim3(256), 0, stream>>>(Wv, Wo, Whi, Wlo);
    bvo_kernel<<<dim3(8),   dim3(256), 0, stream>>>(bv, bo, Wo, bvo);
    packwf1_fp8<<<dim3(2048), dim3(64), 0, stream>>>(Wf1, Pf8);
    smain<<<dim3(256), dim3(1024), 0, stream>>>(
        init_state, acts, Wa, ba, ln1g, ln1b, ln2g, ln2b,
        Wf1, bf1, Wf2, bf2, lifth, Wr, br, Whi, Wlo, Pf8, bvo,
        out_states, out_rewards, out_final);
}